// Round 15
// baseline (223.959 us; speedup 1.0000x reference)
//
#include <hip/hip_runtime.h>
#include <cmath>

typedef unsigned short u16;
typedef __attribute__((ext_vector_type(8))) short bf16x8;
typedef __attribute__((ext_vector_type(4))) float f32x4;
typedef __attribute__((ext_vector_type(16))) float f32x16;

#define MFMA(a,b,c)   __builtin_amdgcn_mfma_f32_16x16x32_bf16((a),(b),(c),0,0,0)
#define MFMA32(a,b,c) __builtin_amdgcn_mfma_f32_32x32x16_bf16((a),(b),(c),0,0,0)

__device__ __forceinline__ float bf2f(u16 u){ return __uint_as_float(((unsigned)u)<<16); }
__device__ __forceinline__ u16 f2bf(float f){
  unsigned x = __float_as_uint(f);
  return (u16)((x + 0x7FFFu + ((x>>16)&1u)) >> 16);
}

__device__ __forceinline__ void gll16(const u16* g, u16* l){
  __builtin_amdgcn_global_load_lds((const __attribute__((address_space(1))) unsigned*)g,
                                   (__attribute__((address_space(3))) unsigned*)l, 16, 0, 0);
}

// ---------- merged prep: weight transpose/re-layout + router-weight hi/lo + regb ----------
// blocks 0..191: w1 (E,D,H) -> w1t2[e][kd][h][d&15]; 192..383: w2 -> w2t2[e][kh][d][h&15];
// 384..647: rw1 hi/lo + regime bias fold.
__global__ __launch_bounds__(256) void k_prep(const float* __restrict__ w1,
        const float* __restrict__ w2, u16* __restrict__ w1t2, u16* __restrict__ w2t2,
        const float* __restrict__ rw1, const float* __restrict__ rb1,
        const float* __restrict__ regime,
        u16* __restrict__ rwh, u16* __restrict__ rwl, float* __restrict__ regb){
  int b = blockIdx.x;
  if (b >= 384){
    int idx = (b-384)*256 + threadIdx.x;
    if (idx < 65536){
      int dd = idx & 255, j = idx >> 8;
      float w = rw1[dd*256 + j];
      u16 hi = f2bf(w);
      rwh[idx] = hi;
      rwl[idx] = f2bf(w - bf2f(hi));
    } else {
      int i = idx - 65536; int j = i & 255, bb = i >> 8;
      float v = rb1[j];
      #pragma unroll
      for (int r=0;r<5;++r) v += regime[bb*5+r]*rw1[(256+r)*256 + j];
      regb[bb*256 + j] = v;
    }
    return;
  }
  __shared__ u16 t[64][66];
  int c0 = threadIdx.x & 63, r0 = threadIdx.x >> 6;
  if (b < 192){            // w1: src (D=256 x H=512)
    int e = b >> 5, tl = b & 31;
    int tr = (tl >> 3) << 6, tc = (tl & 7) << 6;
    const float* src = w1 + (size_t)e*131072;
    u16* dst = w1t2 + (size_t)e*131072;
    #pragma unroll
    for (int i=0;i<16;++i){
      int r = r0 + i*4;
      t[c0][r] = f2bf(src[(size_t)(tr+r)*512 + tc + c0]);
    }
    __syncthreads();
    #pragma unroll
    for (int i=0;i<16;++i){
      int cc = r0 + i*4;
      int h = tc + cc, d = tr + c0;
      dst[(size_t)((d>>4)*512 + h)*16 + (d&15)] = t[cc][c0];
    }
  } else {                 // w2: src (H=512 x D=256)
    int bb = b - 192;
    int e = bb >> 5, tl = bb & 31;
    int tr = (tl >> 2) << 6, tc = (tl & 3) << 6;
    const float* src = w2 + (size_t)e*131072;
    u16* dst = w2t2 + (size_t)e*131072;
    #pragma unroll
    for (int i=0;i<16;++i){
      int r = r0 + i*4;
      t[c0][r] = f2bf(src[(size_t)(tr+r)*256 + tc + c0]);
    }
    __syncthreads();
    #pragma unroll
    for (int i=0;i<16;++i){
      int cc = r0 + i*4;
      int d = tc + cc, h = tr + c0;
      dst[(size_t)((h>>4)*256 + d)*16 + (h&15)] = t[cc][c0];
    }
  }
}

// ---------- fused LN + router GEMM + logits + top2 + aux (hid stays in LDS) ----------
__global__ __launch_bounds__(256,2) void k_router(const float* __restrict__ x,
        const float* __restrict__ lng, const float* __restrict__ lnb,
        const u16* __restrict__ rwh, const u16* __restrict__ rwl,
        const float* __restrict__ regb,
        const float* __restrict__ rw2, const float* __restrict__ rb2,
        u16* __restrict__ xh, float* __restrict__ selw, float* __restrict__ partials){
  __shared__ __align__(16) u16 buf[33792];   // ash | asl, later reused as fbuf (f32 hid)
  __shared__ float psum[6], pcnt[6];
  u16* ash = buf;
  u16* asl = buf + 16896;
  float* fbuf = (float*)buf;                  // [t][j], row stride 257 f32
  int tid = threadIdx.x;
  if (tid < 6){ psum[tid]=0.f; pcnt[tid]=0.f; }
  int lane = tid & 63, wv = tid >> 6;
  int lr = lane & 15, lg = lane >> 4;
  int tb = blockIdx.x * 64;
  // ---- LayerNorm (4 threads per token), write hi/lo to LDS + xh to global ----
  {
    int t4 = tid >> 2, part = tid & 3;
    const float4* xrow = (const float4*)(x + (size_t)(tb+t4)*256 + part*64);
    float s=0.f, ss=0.f;
    #pragma unroll 4
    for (int j=0;j<16;++j){
      float4 v = xrow[j];
      s  += v.x+v.y+v.z+v.w;
      ss += v.x*v.x+v.y*v.y+v.z*v.z+v.w*v.w;
    }
    s += __shfl_xor(s,1);  s += __shfl_xor(s,2);
    ss += __shfl_xor(ss,1); ss += __shfl_xor(ss,2);
    float mu  = s*(1.f/256.f);
    float inv = 1.f/sqrtf(ss*(1.f/256.f) - mu*mu + 1e-5f);
    const float4* gv4 = (const float4*)(lng + part*64);
    const float4* bv4 = (const float4*)(lnb + part*64);
    ushort4* xhrow = (ushort4*)(xh + (size_t)(tb+t4)*256 + part*64);
    #pragma unroll 4
    for (int j=0;j<16;++j){
      float4 v = xrow[j];
      float4 gv = gv4[j], bv = bv4[j];
      float xn[4] = { (v.x-mu)*inv*gv.x+bv.x, (v.y-mu)*inv*gv.y+bv.y,
                      (v.z-mu)*inv*gv.z+bv.z, (v.w-mu)*inv*gv.w+bv.w };
      u16 h[4], l[4];
      #pragma unroll
      for (int q=0;q<4;++q){ h[q]=f2bf(xn[q]); l[q]=f2bf(xn[q]-bf2f(h[q])); }
      ushort4 hh = make_ushort4(h[0],h[1],h[2],h[3]);
      ushort4 ll = make_ushort4(l[0],l[1],l[2],l[3]);
      xhrow[j] = hh;
      *(ushort4*)&ash[t4*264 + part*64 + j*4] = hh;
      *(ushort4*)&asl[t4*264 + part*64 + j*4] = ll;
    }
  }
  __syncthreads();
  f32x4 acc[4][4];
  #pragma unroll
  for (int mf=0;mf<4;++mf)
    #pragma unroll
    for (int nf=0;nf<4;++nf) acc[mf][nf] = (f32x4){0.f,0.f,0.f,0.f};

  const u16* bhb = rwh + (size_t)wv*64*256;
  const u16* blb = rwl + (size_t)wv*64*256;
  #pragma unroll
  for (int kt=0;kt<8;++kt){
    bf16x8 ah[4], al[4], bh[4], bl[4];
    #pragma unroll
    for (int nf=0;nf<4;++nf){
      bh[nf] = *(const bf16x8*)(bhb + (size_t)(nf*16+lr)*256 + kt*32 + lg*8);
      bl[nf] = *(const bf16x8*)(blb + (size_t)(nf*16+lr)*256 + kt*32 + lg*8);
    }
    #pragma unroll
    for (int mf=0;mf<4;++mf){
      ah[mf] = *(const bf16x8*)(&ash[(mf*16+lr)*264 + kt*32 + lg*8]);
      al[mf] = *(const bf16x8*)(&asl[(mf*16+lr)*264 + kt*32 + lg*8]);
    }
    #pragma unroll
    for (int mf=0;mf<4;++mf)
      #pragma unroll
      for (int nf=0;nf<4;++nf){
        acc[mf][nf] = MFMA(ah[mf], bh[nf], acc[mf][nf]);
        acc[mf][nf] = MFMA(al[mf], bh[nf], acc[mf][nf]);
        acc[mf][nf] = MFMA(ah[mf], bl[nf], acc[mf][nf]);
      }
  }
  __syncthreads();   // all waves done reading ash/asl before fbuf overwrite
  int b = tb >> 12;
  #pragma unroll
  for (int mf=0;mf<4;++mf)
    #pragma unroll
    for (int nf=0;nf<4;++nf){
      int j = wv*64 + nf*16 + lr;
      float rbv = regb[b*256 + j];
      #pragma unroll
      for (int r=0;r<4;++r){
        int tl_ = mf*16 + lg*4 + r;
        float v = acc[mf][nf][r] + rbv;
        fbuf[tl_*257 + j] = v/(1.f+__expf(-v));
      }
    }
  __syncthreads();   // hid ready in LDS
  // ---- logits: 4 lanes per token ----
  int t4 = tid >> 2, part = tid & 3;
  float lacc[6] = {0.f,0.f,0.f,0.f,0.f,0.f};
  const float* hrow = fbuf + t4*257 + part*64;
  for (int jj=0;jj<64;++jj){
    float hv = hrow[jj];
    int j = part*64 + jj;
    #pragma unroll
    for (int e=0;e<6;++e) lacc[e] += hv*rw2[j*6+e];
  }
  #pragma unroll
  for (int m=1;m<4;m<<=1)
    #pragma unroll
    for (int e=0;e<6;++e) lacc[e] += __shfl_xor(lacc[e], m);
  if (part == 0){
    float lgv[6];
    #pragma unroll
    for (int e=0;e<6;++e) lgv[e] = lacc[e] + rb2[e];
    int i0=0; float v0=lgv[0];
    #pragma unroll
    for (int e=1;e<6;++e) if (lgv[e] > v0){ v0=lgv[e]; i0=e; }
    int i1=-1; float v1=-1e30f;
    #pragma unroll
    for (int e=0;e<6;++e) if (e!=i0 && lgv[e] > v1){ v1=lgv[e]; i1=e; }
    float ex = expf(v1-v0);
    float w0 = 1.f/(1.f+ex), w1 = ex/(1.f+ex);
    #pragma unroll
    for (int e=0;e<6;++e) selw[(size_t)(tb+t4)*6+e] = (e==i0)? w0 : (e==i1)? w1 : 0.f;
    float ps=0.f, p[6];
    #pragma unroll
    for (int e=0;e<6;++e){ p[e]=expf(lgv[e]-v0); ps+=p[e]; }
    float rinv = 1.f/ps;
    #pragma unroll
    for (int e=0;e<6;++e) atomicAdd(&psum[e], p[e]*rinv);
    atomicAdd(&pcnt[i0], 1.f);
  }
  __syncthreads();
  if (tid < 6){
    partials[blockIdx.x*12 + tid] = psum[tid];
    partials[blockIdx.x*12 + 6 + tid] = pcnt[tid];
  }
}

__global__ __launch_bounds__(256) void k_aux(const float* __restrict__ partials, float* __restrict__ outp){
  __shared__ float a[12];
  int tid = threadIdx.x;
  if (tid < 12) a[tid] = 0.f;
  __syncthreads();
  int col = tid & 15, seg = tid >> 4;
  if (col < 12){
    float s = 0.f;
    for (int i=seg; i<512; i+=16) s += partials[i*12+col];
    atomicAdd(&a[col], s);
  }
  __syncthreads();
  if (tid==0){
    float aux=0.f;
    #pragma unroll
    for (int e=0;e<6;++e) aux += a[e]*a[6+e];
    aux *= 0.01f*6.f/(32768.f*32768.f);
    outp[8388608] = aux;
  }
}

// ---------- fused all-expert MLP: write-late epilogue + setprio (r14 base) ----------
// 256 blocks (1/CU), 8 waves, launch_bounds(512,2). Slot-major LDS (conflict-free):
//   xs [s=0..31][tok=0..127] 16B cells -> u16 idx = s*1024 + tok*8            (64 KB)
//   hs [sh=0..31][tok=0..127] at +32768 (per h-half; stores g*silu)           (64 KB)
// Epilogue computed to regs BEFORE the hs-release barrier (overlaps other waves'
// MFMAs); only the 16 ds_write_b64 sit between the two barriers (T14).
__global__ __launch_bounds__(512,2) void k_experts(const u16* __restrict__ xh,
        const u16* __restrict__ w1t2, const u16* __restrict__ w2t2,
        const float* __restrict__ b1g, const float* __restrict__ b2g,
        const float* __restrict__ selw, const float* __restrict__ xg,
        float* __restrict__ outp){
  __shared__ u16 lds[65536];
  __shared__ float wsl[768];
  int tid = threadIdx.x;
  int lane = tid & 63, wv = tid >> 6;
  int l31 = lane & 31, l5 = lane >> 5;
  int tb = blockIdx.x * 128;

  #pragma unroll
  for (int it=0; it<8; ++it){
    int gcell = it*512 + tid;
    int s = gcell >> 7, tok = gcell & 127;
    gll16(xh + (size_t)(tb+tok)*256 + s*8, lds + gcell*8);
  }
  for (int i=tid;i<768;i+=512) wsl[i] = selw[(size_t)tb*6 + i];
  __syncthreads();

  f32x16 a2[4];
  #pragma unroll
  for (int tt=0;tt<4;++tt) a2[tt] = (f32x16)(0.f);

  for (int e=0;e<6;++e){
    #pragma unroll
    for (int hh=0;hh<2;++hh){
      // ---- GEMM1: wave owns 32 h-rows, K=256, depth-4 prefetch ----
      f32x16 a1[4];
      #pragma unroll
      for (int tt=0;tt<4;++tt) a1[tt] = (f32x16)(0.f);
      const u16* w1b = w1t2 + (size_t)e*131072 + (size_t)(hh*256 + wv*32 + l31)*16 + l5*8;
      {
        bf16x8 p0 = *(const bf16x8*)(w1b);
        bf16x8 p1 = *(const bf16x8*)(w1b + 8192);
        bf16x8 p2 = *(const bf16x8*)(w1b + 16384);
        bf16x8 p3 = *(const bf16x8*)(w1b + 24576);
        __builtin_amdgcn_s_setprio(1);
        #pragma unroll
        for (int ks=0; ks<16; ++ks){
          bf16x8 cur = p0; p0 = p1; p1 = p2; p2 = p3;
          if (ks+4 < 16) p3 = *(const bf16x8*)(w1b + (ks+4)*8192);
          #pragma unroll
          for (int tt=0;tt<4;++tt){
            bf16x8 bx = *(const bf16x8*)&lds[(ks*2+l5)*1024 + (tt*32+l31)*8];
            a1[tt] = MFMA32(cur, bx, a1[tt]);
          }
        }
        __builtin_amdgcn_s_setprio(0);
      }
      // ---- epilogue compute (pre-barrier): bias + silu + gate -> pk regs ----
      uint2 pk[4][4];
      #pragma unroll
      for (int rq=0;rq<4;++rq){
        float4 b4 = *(const float4*)(b1g + (size_t)e*512 + hh*256 + wv*32 + rq*8 + l5*4);
        float bb[4] = {b4.x,b4.y,b4.z,b4.w};
        #pragma unroll
        for (int tt=0;tt<4;++tt){
          float g = wsl[(tt*32+l31)*6 + e];
          float sv[4];
          #pragma unroll
          for (int q=0;q<4;++q){
            float v = a1[tt][rq*4+q] + bb[q];
            sv[q] = g * (v/(1.f+__expf(-v)));
          }
          unsigned pA, pB;
          asm("v_cvt_pk_bf16_f32 %0, %1, %2" : "=v"(pA) : "v"(sv[0]), "v"(sv[1]));
          asm("v_cvt_pk_bf16_f32 %0, %1, %2" : "=v"(pB) : "v"(sv[2]), "v"(sv[3]));
          pk[rq][tt] = make_uint2(pA,pB);
        }
      }
      __syncthreads();   // previous GEMM2's hs readers done
      #pragma unroll
      for (int rq=0;rq<4;++rq)
        #pragma unroll
        for (int tt=0;tt<4;++tt)
          *(uint2*)&lds[32768 + (wv*4+rq)*1024 + (tt*32+l31)*8 + l5*4] = pk[rq][tt];
      __syncthreads();   // hs ready
      // ---- GEMM2: wave owns 32 d-rows, K = this h-half (256), accumulate into a2 ----
      const u16* w2b = w2t2 + (size_t)e*131072 + (size_t)(hh*16)*4096 + (size_t)(wv*32 + l31)*16 + l5*8;
      {
        bf16x8 p0 = *(const bf16x8*)(w2b);
        bf16x8 p1 = *(const bf16x8*)(w2b + 4096);
        bf16x8 p2 = *(const bf16x8*)(w2b + 8192);
        bf16x8 p3 = *(const bf16x8*)(w2b + 12288);
        __builtin_amdgcn_s_setprio(1);
        #pragma unroll
        for (int ks=0; ks<16; ++ks){
          bf16x8 cur = p0; p0 = p1; p1 = p2; p2 = p3;
          if (ks+4 < 16) p3 = *(const bf16x8*)(w2b + (ks+4)*4096);
          #pragma unroll
          for (int tt=0;tt<4;++tt){
            bf16x8 hf = *(const bf16x8*)&lds[32768 + (ks*2+l5)*1024 + (tt*32+l31)*8];
            a2[tt] = MFMA32(cur, hf, a2[tt]);
          }
        }
        __builtin_amdgcn_s_setprio(0);
      }
    }
  }
  // ---- rank-6 b2 correction ----
  #pragma unroll
  for (int e=0;e<6;++e){
    #pragma unroll
    for (int tt=0;tt<4;++tt){
      float g = wsl[(tt*32+l31)*6 + e];
      #pragma unroll
      for (int rq=0;rq<4;++rq){
        float4 b4 = *(const float4*)(b2g + (size_t)e*256 + wv*32 + rq*8 + l5*4);
        a2[tt][rq*4+0] += g*b4.x; a2[tt][rq*4+1] += g*b4.y;
        a2[tt][rq*4+2] += g*b4.z; a2[tt][rq*4+3] += g*b4.w;
      }
    }
  }
  // ---- residual + store ----
  #pragma unroll
  for (int tt=0;tt<4;++tt){
    int t = tb + tt*32 + l31;
    #pragma unroll
    for (int rq=0;rq<4;++rq){
      int d = wv*32 + rq*8 + l5*4;
      float4 xv = *(const float4*)(xg + (size_t)t*256 + d);
      float4 o;
      o.x = xv.x + a2[tt][rq*4+0];
      o.y = xv.y + a2[tt][rq*4+1];
      o.z = xv.z + a2[tt][rq*4+2];
      o.w = xv.w + a2[tt][rq*4+3];
      *(float4*)(outp + (size_t)t*256 + d) = o;
    }
  }
}

extern "C" void kernel_launch(void* const* d_in, const int* in_sizes, int n_in,
                              void* d_out, int out_size, void* d_ws, size_t ws_size,
                              hipStream_t stream){
  const float* x      = (const float*)d_in[0];
  const float* regime = (const float*)d_in[1];
  const float* ln_g   = (const float*)d_in[2];
  const float* ln_b   = (const float*)d_in[3];
  const float* w1     = (const float*)d_in[4];
  const float* b1     = (const float*)d_in[5];
  const float* w2     = (const float*)d_in[6];
  const float* b2     = (const float*)d_in[7];
  const float* rw1    = (const float*)d_in[8];
  const float* rb1    = (const float*)d_in[9];
  const float* rw2    = (const float*)d_in[10];
  const float* rb2    = (const float*)d_in[11];
  float* outp = (float*)d_out;
  char* ws = (char*)d_ws;

  u16*   w1t2 = (u16*)(ws + 0);          // 1,572,864
  u16*   w2t2 = (u16*)(ws + 1572864);    // 1,572,864
  u16*   rwh  = (u16*)(ws + 3145728);    // 131,072
  u16*   rwl  = (u16*)(ws + 3276800);    // 131,072
  float* regb = (float*)(ws + 3407872);  // 8,192
  u16*   xh   = (u16*)(ws + 3416064);    // 16,777,216
  float* part = (float*)(ws + 36970496); // 24,576
  float* selw = (float*)(ws + 70524928); // 786,432

  k_prep<<<648,256,0,stream>>>(w1, w2, w1t2, w2t2, rw1, rb1, regime, rwh, rwl, regb);
  k_router<<<512,256,0,stream>>>(x, ln_g, ln_b, rwh, rwl, regb, rw2, rb2, xh, selw, part);
  k_aux<<<1,256,0,stream>>>(part, outp);
  k_experts<<<256,512,0,stream>>>(xh, w1t2, w2t2, b1, b2, selw, x, outp);
}

// Round 16
// 209.434 us; speedup vs baseline: 1.0694x; 1.0694x over previous
//
#include <hip/hip_runtime.h>
#include <cmath>

typedef unsigned short u16;
typedef __attribute__((ext_vector_type(8))) short bf16x8;
typedef __attribute__((ext_vector_type(4))) float f32x4;
typedef __attribute__((ext_vector_type(16))) float f32x16;

#define MFMA(a,b,c)   __builtin_amdgcn_mfma_f32_16x16x32_bf16((a),(b),(c),0,0,0)
#define MFMA32(a,b,c) __builtin_amdgcn_mfma_f32_32x32x16_bf16((a),(b),(c),0,0,0)

__device__ __forceinline__ float bf2f(u16 u){ return __uint_as_float(((unsigned)u)<<16); }
__device__ __forceinline__ u16 f2bf(float f){
  unsigned x = __float_as_uint(f);
  return (u16)((x + 0x7FFFu + ((x>>16)&1u)) >> 16);
}

__device__ __forceinline__ void gll16(const u16* g, u16* l){
  __builtin_amdgcn_global_load_lds((const __attribute__((address_space(1))) unsigned*)g,
                                   (__attribute__((address_space(3))) unsigned*)l, 16, 0, 0);
}

// ---------- merged prep: weight transpose/re-layout + router-weight hi/lo + regb ----------
__global__ __launch_bounds__(256) void k_prep(const float* __restrict__ w1,
        const float* __restrict__ w2, u16* __restrict__ w1t2, u16* __restrict__ w2t2,
        const float* __restrict__ rw1, const float* __restrict__ rb1,
        const float* __restrict__ regime,
        u16* __restrict__ rwh, u16* __restrict__ rwl, float* __restrict__ regb){
  int b = blockIdx.x;
  if (b >= 384){
    int idx = (b-384)*256 + threadIdx.x;
    if (idx < 65536){
      int dd = idx & 255, j = idx >> 8;
      float w = rw1[dd*256 + j];
      u16 hi = f2bf(w);
      rwh[idx] = hi;
      rwl[idx] = f2bf(w - bf2f(hi));
    } else {
      int i = idx - 65536; int j = i & 255, bb = i >> 8;
      float v = rb1[j];
      #pragma unroll
      for (int r=0;r<5;++r) v += regime[bb*5+r]*rw1[(256+r)*256 + j];
      regb[bb*256 + j] = v;
    }
    return;
  }
  __shared__ u16 t[64][66];
  int c0 = threadIdx.x & 63, r0 = threadIdx.x >> 6;
  if (b < 192){            // w1: src (D=256 x H=512)
    int e = b >> 5, tl = b & 31;
    int tr = (tl >> 3) << 6, tc = (tl & 7) << 6;
    const float* src = w1 + (size_t)e*131072;
    u16* dst = w1t2 + (size_t)e*131072;
    #pragma unroll
    for (int i=0;i<16;++i){
      int r = r0 + i*4;
      t[c0][r] = f2bf(src[(size_t)(tr+r)*512 + tc + c0]);
    }
    __syncthreads();
    #pragma unroll
    for (int i=0;i<16;++i){
      int cc = r0 + i*4;
      int h = tc + cc, d = tr + c0;
      dst[(size_t)((d>>4)*512 + h)*16 + (d&15)] = t[cc][c0];
    }
  } else {                 // w2: src (H=512 x D=256)
    int bb = b - 192;
    int e = bb >> 5, tl = bb & 31;
    int tr = (tl >> 2) << 6, tc = (tl & 3) << 6;
    const float* src = w2 + (size_t)e*131072;
    u16* dst = w2t2 + (size_t)e*131072;
    #pragma unroll
    for (int i=0;i<16;++i){
      int r = r0 + i*4;
      t[c0][r] = f2bf(src[(size_t)(tr+r)*256 + tc + c0]);
    }
    __syncthreads();
    #pragma unroll
    for (int i=0;i<16;++i){
      int cc = r0 + i*4;
      int d = tc + cc, h = tr + c0;
      dst[(size_t)((h>>4)*256 + d)*16 + (h&15)] = t[cc][c0];
    }
  }
}

// ---------- fused LN + router GEMM + logits + top2 + list build + aux ----------
__global__ __launch_bounds__(256,2) void k_router(const float* __restrict__ x,
        const float* __restrict__ lng, const float* __restrict__ lnb,
        const u16* __restrict__ rwh, const u16* __restrict__ rwl,
        const float* __restrict__ regb,
        const float* __restrict__ rw2, const float* __restrict__ rb2,
        u16* __restrict__ xh, int* __restrict__ list, float* __restrict__ gl,
        int* __restrict__ ppos, int* __restrict__ cnt, float* __restrict__ partials){
  __shared__ __align__(16) u16 buf[33792];   // ash | asl, later reused as fbuf (f32 hid)
  __shared__ float psum[6], pcnt[6];
  __shared__ int lcnt[6], lbase[6];
  u16* ash = buf;
  u16* asl = buf + 16896;
  float* fbuf = (float*)buf;                  // [t][j], row stride 257 f32
  int tid = threadIdx.x;
  if (tid < 6){ psum[tid]=0.f; pcnt[tid]=0.f; lcnt[tid]=0; }
  int lane = tid & 63, wv = tid >> 6;
  int lr = lane & 15, lg = lane >> 4;
  int tb = blockIdx.x * 64;
  // ---- LayerNorm (4 threads per token), write hi/lo to LDS + xh to global ----
  {
    int t4 = tid >> 2, part = tid & 3;
    const float4* xrow = (const float4*)(x + (size_t)(tb+t4)*256 + part*64);
    float s=0.f, ss=0.f;
    #pragma unroll 4
    for (int j=0;j<16;++j){
      float4 v = xrow[j];
      s  += v.x+v.y+v.z+v.w;
      ss += v.x*v.x+v.y*v.y+v.z*v.z+v.w*v.w;
    }
    s += __shfl_xor(s,1);  s += __shfl_xor(s,2);
    ss += __shfl_xor(ss,1); ss += __shfl_xor(ss,2);
    float mu  = s*(1.f/256.f);
    float inv = 1.f/sqrtf(ss*(1.f/256.f) - mu*mu + 1e-5f);
    const float4* gv4 = (const float4*)(lng + part*64);
    const float4* bv4 = (const float4*)(lnb + part*64);
    ushort4* xhrow = (ushort4*)(xh + (size_t)(tb+t4)*256 + part*64);
    #pragma unroll 4
    for (int j=0;j<16;++j){
      float4 v = xrow[j];
      float4 gv = gv4[j], bv = bv4[j];
      float xn[4] = { (v.x-mu)*inv*gv.x+bv.x, (v.y-mu)*inv*gv.y+bv.y,
                      (v.z-mu)*inv*gv.z+bv.z, (v.w-mu)*inv*gv.w+bv.w };
      u16 h[4], l[4];
      #pragma unroll
      for (int q=0;q<4;++q){ h[q]=f2bf(xn[q]); l[q]=f2bf(xn[q]-bf2f(h[q])); }
      ushort4 hh = make_ushort4(h[0],h[1],h[2],h[3]);
      ushort4 ll = make_ushort4(l[0],l[1],l[2],l[3]);
      xhrow[j] = hh;
      *(ushort4*)&ash[t4*264 + part*64 + j*4] = hh;
      *(ushort4*)&asl[t4*264 + part*64 + j*4] = ll;
    }
  }
  __syncthreads();
  f32x4 acc[4][4];
  #pragma unroll
  for (int mf=0;mf<4;++mf)
    #pragma unroll
    for (int nf=0;nf<4;++nf) acc[mf][nf] = (f32x4){0.f,0.f,0.f,0.f};

  const u16* bhb = rwh + (size_t)wv*64*256;
  const u16* blb = rwl + (size_t)wv*64*256;
  #pragma unroll
  for (int kt=0;kt<8;++kt){
    bf16x8 ah[4], al[4], bh[4], bl[4];
    #pragma unroll
    for (int nf=0;nf<4;++nf){
      bh[nf] = *(const bf16x8*)(bhb + (size_t)(nf*16+lr)*256 + kt*32 + lg*8);
      bl[nf] = *(const bf16x8*)(blb + (size_t)(nf*16+lr)*256 + kt*32 + lg*8);
    }
    #pragma unroll
    for (int mf=0;mf<4;++mf){
      ah[mf] = *(const bf16x8*)(&ash[(mf*16+lr)*264 + kt*32 + lg*8]);
      al[mf] = *(const bf16x8*)(&asl[(mf*16+lr)*264 + kt*32 + lg*8]);
    }
    #pragma unroll
    for (int mf=0;mf<4;++mf)
      #pragma unroll
      for (int nf=0;nf<4;++nf){
        acc[mf][nf] = MFMA(ah[mf], bh[nf], acc[mf][nf]);
        acc[mf][nf] = MFMA(al[mf], bh[nf], acc[mf][nf]);
        acc[mf][nf] = MFMA(ah[mf], bl[nf], acc[mf][nf]);
      }
  }
  __syncthreads();   // all waves done reading ash/asl before fbuf overwrite
  int b = tb >> 12;
  #pragma unroll
  for (int mf=0;mf<4;++mf)
    #pragma unroll
    for (int nf=0;nf<4;++nf){
      int j = wv*64 + nf*16 + lr;
      float rbv = regb[b*256 + j];
      #pragma unroll
      for (int r=0;r<4;++r){
        int tl_ = mf*16 + lg*4 + r;
        float v = acc[mf][nf][r] + rbv;
        fbuf[tl_*257 + j] = v/(1.f+__expf(-v));
      }
    }
  __syncthreads();   // hid ready in LDS
  // ---- logits: 4 lanes per token ----
  int t4 = tid >> 2, part = tid & 3;
  float lacc[6] = {0.f,0.f,0.f,0.f,0.f,0.f};
  const float* hrow = fbuf + t4*257 + part*64;
  for (int jj=0;jj<64;++jj){
    float hv = hrow[jj];
    int j = part*64 + jj;
    #pragma unroll
    for (int e=0;e<6;++e) lacc[e] += hv*rw2[j*6+e];
  }
  #pragma unroll
  for (int m=1;m<4;m<<=1)
    #pragma unroll
    for (int e=0;e<6;++e) lacc[e] += __shfl_xor(lacc[e], m);
  int i0=0, i1=0, q0=0, q1=0;
  float w0=0.f, w1v=0.f;
  if (part == 0){
    float lgv[6];
    #pragma unroll
    for (int e=0;e<6;++e) lgv[e] = lacc[e] + rb2[e];
    float v0=lgv[0];
    #pragma unroll
    for (int e=1;e<6;++e) if (lgv[e] > v0){ v0=lgv[e]; i0=e; }
    float v1=-1e30f; i1 = -1;
    #pragma unroll
    for (int e=0;e<6;++e) if (e!=i0 && lgv[e] > v1){ v1=lgv[e]; i1=e; }
    float ex = expf(v1-v0);
    w0 = 1.f/(1.f+ex); w1v = ex/(1.f+ex);
    q0 = atomicAdd(&lcnt[i0], 1);
    q1 = atomicAdd(&lcnt[i1], 1);
    float ps=0.f, p[6];
    #pragma unroll
    for (int e=0;e<6;++e){ p[e]=expf(lgv[e]-v0); ps+=p[e]; }
    float rinv = 1.f/ps;
    #pragma unroll
    for (int e=0;e<6;++e) atomicAdd(&psum[e], p[e]*rinv);
    atomicAdd(&pcnt[i0], 1.f);
  }
  __syncthreads();
  if (tid < 6) lbase[tid] = atomicAdd(&cnt[tid], lcnt[tid]);
  __syncthreads();
  if (part == 0){
    int t = tb + t4;
    int pos0 = i0*32768 + lbase[i0] + q0;
    int pos1 = i1*32768 + lbase[i1] + q1;
    list[pos0] = t; gl[pos0] = w0;
    list[pos1] = t; gl[pos1] = w1v;
    ppos[t*2]   = pos0;
    ppos[t*2+1] = pos1;
  }
  if (tid < 6){
    partials[blockIdx.x*12 + tid] = psum[tid];
    partials[blockIdx.x*12 + 6 + tid] = pcnt[tid];
  }
}

__global__ __launch_bounds__(256) void k_aux(const float* __restrict__ partials, float* __restrict__ outp){
  __shared__ float a[12];
  int tid = threadIdx.x;
  if (tid < 12) a[tid] = 0.f;
  __syncthreads();
  int col = tid & 15, seg = tid >> 4;
  if (col < 12){
    float s = 0.f;
    for (int i=seg; i<512; i+=16) s += partials[i*12+col];
    atomicAdd(&a[col], s);
  }
  __syncthreads();
  if (tid==0){
    float aux=0.f;
    #pragma unroll
    for (int e=0;e<6;++e) aux += a[e]*a[6+e];
    aux *= 0.01f*6.f/(32768.f*32768.f);
    outp[8388608] = aux;
  }
}

// ---------- sparse expert MLP: one (expert, 128-token chunk) per block ----------
// Gathered tokens; r14-verified GEMM pipeline for a single expert; gated bf16
// output rows (incl. g*b2) to eo[pair_pos][256] via LDS bounce (coalesced).
__global__ __launch_bounds__(512,2) void k_experts(const u16* __restrict__ xh,
        const u16* __restrict__ w1t2, const u16* __restrict__ w2t2,
        const float* __restrict__ b1g, const float* __restrict__ b2g,
        const int* __restrict__ list, const float* __restrict__ gl,
        const int* __restrict__ cnt, u16* __restrict__ eo){
  __shared__ u16 lds[65536];
  __shared__ int tkid[128];
  __shared__ float tg[128];
  int tid = threadIdx.x;
  int lane = tid & 63, wv = tid >> 6;
  int l31 = lane & 31, l5 = lane >> 5;
  int e = blockIdx.x >> 8, chunk = blockIdx.x & 255;
  int gbase = chunk << 7;
  int cnte = cnt[e];
  if (gbase >= cnte) return;
  int ebase = e << 15;
  if (tid < 128){
    int p = gbase + tid;
    int cl = (p < cnte) ? p : (cnte - 1);
    tkid[tid] = list[ebase + cl];
    tg[tid]   = (p < cnte) ? gl[ebase + p] : 0.f;
  }
  __syncthreads();
  // gather xs: linear LDS dest (slot-major), per-lane global source rows
  #pragma unroll
  for (int it=0; it<8; ++it){
    int gcell = it*512 + tid;
    int s = gcell >> 7, tok = gcell & 127;
    gll16(xh + (size_t)tkid[tok]*256 + s*8, lds + gcell*8);
  }
  __syncthreads();

  f32x16 a2[4];
  #pragma unroll
  for (int tt=0;tt<4;++tt) a2[tt] = (f32x16)(0.f);

  #pragma unroll
  for (int hh=0;hh<2;++hh){
    // ---- GEMM1: wave owns 32 h-rows, K=256, depth-4 prefetch ----
    f32x16 a1[4];
    #pragma unroll
    for (int tt=0;tt<4;++tt) a1[tt] = (f32x16)(0.f);
    const u16* w1b = w1t2 + (size_t)e*131072 + (size_t)(hh*256 + wv*32 + l31)*16 + l5*8;
    {
      bf16x8 p0 = *(const bf16x8*)(w1b);
      bf16x8 p1 = *(const bf16x8*)(w1b + 8192);
      bf16x8 p2 = *(const bf16x8*)(w1b + 16384);
      bf16x8 p3 = *(const bf16x8*)(w1b + 24576);
      #pragma unroll
      for (int ks=0; ks<16; ++ks){
        bf16x8 cur = p0; p0 = p1; p1 = p2; p2 = p3;
        if (ks+4 < 16) p3 = *(const bf16x8*)(w1b + (ks+4)*8192);
        #pragma unroll
        for (int tt=0;tt<4;++tt){
          bf16x8 bx = *(const bf16x8*)&lds[(ks*2+l5)*1024 + (tt*32+l31)*8];
          a1[tt] = MFMA32(cur, bx, a1[tt]);
        }
      }
    }
    __syncthreads();   // previous hs readers done
    // ---- epilogue: bias + silu, scaled by gate -> hs (cvt_pk pack) ----
    #pragma unroll
    for (int rq=0;rq<4;++rq){
      float4 b4 = *(const float4*)(b1g + (size_t)e*512 + hh*256 + wv*32 + rq*8 + l5*4);
      float bb[4] = {b4.x,b4.y,b4.z,b4.w};
      #pragma unroll
      for (int tt=0;tt<4;++tt){
        float g = tg[tt*32+l31];
        float sv[4];
        #pragma unroll
        for (int q=0;q<4;++q){
          float v = a1[tt][rq*4+q] + bb[q];
          sv[q] = g * (v/(1.f+__expf(-v)));
        }
        unsigned pA, pB;
        asm("v_cvt_pk_bf16_f32 %0, %1, %2" : "=v"(pA) : "v"(sv[0]), "v"(sv[1]));
        asm("v_cvt_pk_bf16_f32 %0, %1, %2" : "=v"(pB) : "v"(sv[2]), "v"(sv[3]));
        *(uint2*)&lds[32768 + (wv*4+rq)*1024 + (tt*32+l31)*8 + l5*4] = make_uint2(pA,pB);
      }
    }
    __syncthreads();   // hs ready
    // ---- GEMM2: wave owns 32 d-rows, K = this h-half (256), accumulate into a2 ----
    const u16* w2b = w2t2 + (size_t)e*131072 + (size_t)(hh*16)*4096 + (size_t)(wv*32 + l31)*16 + l5*8;
    {
      bf16x8 p0 = *(const bf16x8*)(w2b);
      bf16x8 p1 = *(const bf16x8*)(w2b + 4096);
      bf16x8 p2 = *(const bf16x8*)(w2b + 8192);
      bf16x8 p3 = *(const bf16x8*)(w2b + 12288);
      #pragma unroll
      for (int ks=0; ks<16; ++ks){
        bf16x8 cur = p0; p0 = p1; p1 = p2; p2 = p3;
        if (ks+4 < 16) p3 = *(const bf16x8*)(w2b + (ks+4)*4096);
        #pragma unroll
        for (int tt=0;tt<4;++tt){
          bf16x8 hf = *(const bf16x8*)&lds[32768 + (ks*2+l5)*1024 + (tt*32+l31)*8];
          a2[tt] = MFMA32(cur, hf, a2[tt]);
        }
      }
    }
  }
  // ---- g*b2 fold ----
  #pragma unroll
  for (int tt=0;tt<4;++tt){
    float g = tg[tt*32+l31];
    #pragma unroll
    for (int rq=0;rq<4;++rq){
      float4 b4 = *(const float4*)(b2g + (size_t)e*256 + wv*32 + rq*8 + l5*4);
      a2[tt][rq*4+0] += g*b4.x; a2[tt][rq*4+1] += g*b4.y;
      a2[tt][rq*4+2] += g*b4.z; a2[tt][rq*4+3] += g*b4.w;
    }
  }
  // ---- bounce to LDS [tok][264] (bf16), then coalesced row copy to eo ----
  __syncthreads();   // all LDS reads done; bounce overwrites xs/hs start
  #pragma unroll
  for (int tt=0;tt<4;++tt){
    #pragma unroll
    for (int rq=0;rq<4;++rq){
      unsigned pA, pB;
      asm("v_cvt_pk_bf16_f32 %0, %1, %2" : "=v"(pA) : "v"(a2[tt][rq*4+0]), "v"(a2[tt][rq*4+1]));
      asm("v_cvt_pk_bf16_f32 %0, %1, %2" : "=v"(pB) : "v"(a2[tt][rq*4+2]), "v"(a2[tt][rq*4+3]));
      *(uint2*)&lds[(tt*32+l31)*264 + wv*32 + rq*8 + l5*4] = make_uint2(pA,pB);
    }
  }
  __syncthreads();
  for (int i = tid; i < 4096; i += 512){
    int row = i >> 5, col = i & 31;
    uint4 v = *(uint4*)&lds[row*264 + col*8];
    *(uint4*)(eo + ((size_t)(ebase + gbase + row) << 8) + col*8) = v;
  }
}

// ---------- combine: out = x + eo[p0] + eo[p1] ----------
__global__ __launch_bounds__(256) void k_combine(const float* __restrict__ x,
        const u16* __restrict__ eo, const int* __restrict__ ppos,
        float* __restrict__ outp){
  int gid = blockIdx.x*256 + threadIdx.x;
  int t = gid >> 5, dp = gid & 31;
  int d0 = dp*8;
  int p0 = ppos[t*2], p1 = ppos[t*2+1];
  bf16x8 r0 = *(const bf16x8*)(eo + ((size_t)p0 << 8) + d0);
  bf16x8 r1 = *(const bf16x8*)(eo + ((size_t)p1 << 8) + d0);
  const float* xr = x + (size_t)t*256 + d0;
  float4 o0, o1;
  o0.x = xr[0] + bf2f((u16)r0[0]) + bf2f((u16)r1[0]);
  o0.y = xr[1] + bf2f((u16)r0[1]) + bf2f((u16)r1[1]);
  o0.z = xr[2] + bf2f((u16)r0[2]) + bf2f((u16)r1[2]);
  o0.w = xr[3] + bf2f((u16)r0[3]) + bf2f((u16)r1[3]);
  o1.x = xr[4] + bf2f((u16)r0[4]) + bf2f((u16)r1[4]);
  o1.y = xr[5] + bf2f((u16)r0[5]) + bf2f((u16)r1[5]);
  o1.z = xr[6] + bf2f((u16)r0[6]) + bf2f((u16)r1[6]);
  o1.w = xr[7] + bf2f((u16)r0[7]) + bf2f((u16)r1[7]);
  *(float4*)(outp + (size_t)t*256 + d0)     = o0;
  *(float4*)(outp + (size_t)t*256 + d0 + 4) = o1;
}

extern "C" void kernel_launch(void* const* d_in, const int* in_sizes, int n_in,
                              void* d_out, int out_size, void* d_ws, size_t ws_size,
                              hipStream_t stream){
  const float* x      = (const float*)d_in[0];
  const float* regime = (const float*)d_in[1];
  const float* ln_g   = (const float*)d_in[2];
  const float* ln_b   = (const float*)d_in[3];
  const float* w1     = (const float*)d_in[4];
  const float* b1     = (const float*)d_in[5];
  const float* w2     = (const float*)d_in[6];
  const float* b2     = (const float*)d_in[7];
  const float* rw1    = (const float*)d_in[8];
  const float* rb1    = (const float*)d_in[9];
  const float* rw2    = (const float*)d_in[10];
  const float* rb2    = (const float*)d_in[11];
  float* outp = (float*)d_out;
  char* ws = (char*)d_ws;

  u16*   w1t2 = (u16*)(ws + 0);          // 1,572,864
  u16*   w2t2 = (u16*)(ws + 1572864);    // 1,572,864
  u16*   rwh  = (u16*)(ws + 3145728);    // 131,072
  u16*   rwl  = (u16*)(ws + 3276800);    // 131,072
  float* regb = (float*)(ws + 3407872);  // 8,192
  u16*   xh   = (u16*)(ws + 3416064);    // 16,777,216 -> ends 20,193,280
  int*   cnt  = (int*)(ws + 20193280);   // 24 (pad 256)
  int*   list = (int*)(ws + 20193536);   // 786,432
  float* gl   = (float*)(ws + 20979968); // 786,432
  int*   ppos = (int*)(ws + 21766400);   // 262,144
  float* part = (float*)(ws + 22028544); // 24,576
  u16*   eo   = (u16*)(ws + 22053120);   // 33,554,432 -> ends 55,607,552

  hipMemsetAsync(cnt, 0, 24, stream);
  k_prep<<<648,256,0,stream>>>(w1, w2, w1t2, w2t2, rw1, rb1, regime, rwh, rwl, regb);
  k_router<<<512,256,0,stream>>>(x, ln_g, ln_b, rwh, rwl, regb, rw2, rb2,
                                 xh, list, gl, ppos, cnt, part);
  k_aux<<<1,256,0,stream>>>(part, outp);
  k_experts<<<1536,512,0,stream>>>(xh, w1t2, w2t2, b1, b2, list, gl, cnt, eo);
  k_combine<<<4096,256,0,stream>>>(x, eo, ppos, outp);
}

// Round 17
// 169.163 us; speedup vs baseline: 1.3239x; 1.2381x over previous
//
#include <hip/hip_runtime.h>
#include <cmath>

typedef unsigned short u16;
typedef __attribute__((ext_vector_type(8))) short bf16x8;
typedef __attribute__((ext_vector_type(4))) float f32x4;
typedef __attribute__((ext_vector_type(16))) float f32x16;

#define MFMA(a,b,c)   __builtin_amdgcn_mfma_f32_16x16x32_bf16((a),(b),(c),0,0,0)
#define MFMA32(a,b,c) __builtin_amdgcn_mfma_f32_32x32x16_bf16((a),(b),(c),0,0,0)

__device__ __forceinline__ float bf2f(u16 u){ return __uint_as_float(((unsigned)u)<<16); }
__device__ __forceinline__ u16 f2bf(float f){
  unsigned x = __float_as_uint(f);
  return (u16)((x + 0x7FFFu + ((x>>16)&1u)) >> 16);
}

__device__ __forceinline__ void gll16(const u16* g, u16* l){
  __builtin_amdgcn_global_load_lds((const __attribute__((address_space(1))) unsigned*)g,
                                   (__attribute__((address_space(3))) unsigned*)l, 16, 0, 0);
}

// ---------- small prep: rw1 hi/lo split + regime bias fold (router depends on it) ----------
__global__ void k_prep_rw1(const float* __restrict__ rw1, const float* __restrict__ rb1,
                           const float* __restrict__ regime,
                           u16* __restrict__ rwh, u16* __restrict__ rwl,
                           float* __restrict__ regb){
  int idx = blockIdx.x*256 + threadIdx.x;
  if (idx < 65536){
    int dd = idx & 255, j = idx >> 8;
    float w = rw1[dd*256 + j];
    u16 hi = f2bf(w);
    rwh[idx] = hi;
    rwl[idx] = f2bf(w - bf2f(hi));
  } else {
    int i = idx - 65536; int j = i & 255, bb = i >> 8;
    float v = rb1[j];
    #pragma unroll
    for (int r=0;r<5;++r) v += regime[bb*5+r]*rw1[(256+r)*256 + j];
    regb[bb*256 + j] = v;
  }
}

// ---------- fused LN + router GEMM + logits + top2 + PAIR-list build + aux partials
// ---------- blocks >= 512: w1/w2 transpose/re-layout (independent; needed only by experts)
__global__ __launch_bounds__(256,2) void k_router(const float* __restrict__ x,
        const float* __restrict__ lng, const float* __restrict__ lnb,
        const u16* __restrict__ rwh, const u16* __restrict__ rwl,
        const float* __restrict__ regb,
        const float* __restrict__ rw2, const float* __restrict__ rb2,
        u16* __restrict__ xh, int* __restrict__ list, float2* __restrict__ gl2,
        int* __restrict__ cnt, float* __restrict__ partials,
        const float* __restrict__ w1, const float* __restrict__ w2,
        u16* __restrict__ w1t2, u16* __restrict__ w2t2){
  __shared__ __align__(16) u16 buf[33792];   // ash | asl, reused as fbuf / transpose tile
  __shared__ float psum[6], pcnt[6];
  __shared__ int lcnt[15], lbase[15];
  int tid = threadIdx.x;
  if (blockIdx.x >= 512){
    // ---- weight transpose/re-layout (same as verified k_prep) ----
    int b = blockIdx.x - 512;
    u16 (*t)[66] = (u16(*)[66])buf;
    int c0 = tid & 63, r0 = tid >> 6;
    if (b < 192){          // w1 (E,D,H) -> w1t2[e][kd][h][d&15]
      int e = b >> 5, tl = b & 31;
      int tr = (tl >> 3) << 6, tc = (tl & 7) << 6;
      const float* src = w1 + (size_t)e*131072;
      u16* dst = w1t2 + (size_t)e*131072;
      #pragma unroll
      for (int i=0;i<16;++i){
        int r = r0 + i*4;
        t[c0][r] = f2bf(src[(size_t)(tr+r)*512 + tc + c0]);
      }
      __syncthreads();
      #pragma unroll
      for (int i=0;i<16;++i){
        int cc = r0 + i*4;
        int h = tc + cc, d = tr + c0;
        dst[(size_t)((d>>4)*512 + h)*16 + (d&15)] = t[cc][c0];
      }
    } else {               // w2 (E,H,D) -> w2t2[e][kh][d][h&15]
      int bb = b - 192;
      int e = bb >> 5, tl = bb & 31;
      int tr = (tl >> 2) << 6, tc = (tl & 3) << 6;
      const float* src = w2 + (size_t)e*131072;
      u16* dst = w2t2 + (size_t)e*131072;
      #pragma unroll
      for (int i=0;i<16;++i){
        int r = r0 + i*4;
        t[c0][r] = f2bf(src[(size_t)(tr+r)*256 + tc + c0]);
      }
      __syncthreads();
      #pragma unroll
      for (int i=0;i<16;++i){
        int cc = r0 + i*4;
        int d = tc + cc, h = tr + c0;
        dst[(size_t)((h>>4)*256 + d)*16 + (h&15)] = t[cc][c0];
      }
    }
    return;
  }
  u16* ash = buf;
  u16* asl = buf + 16896;
  float* fbuf = (float*)buf;                  // [t][j], row stride 257 f32
  if (tid < 6){ psum[tid]=0.f; pcnt[tid]=0.f; }
  if (tid < 15) lcnt[tid]=0;
  int lane = tid & 63, wv = tid >> 6;
  int lr = lane & 15, lg = lane >> 4;
  int tb = blockIdx.x * 64;
  // ---- LayerNorm (4 threads per token), write hi/lo to LDS + xh to global ----
  {
    int t4 = tid >> 2, part = tid & 3;
    const float4* xrow = (const float4*)(x + (size_t)(tb+t4)*256 + part*64);
    float s=0.f, ss=0.f;
    #pragma unroll 4
    for (int j=0;j<16;++j){
      float4 v = xrow[j];
      s  += v.x+v.y+v.z+v.w;
      ss += v.x*v.x+v.y*v.y+v.z*v.z+v.w*v.w;
    }
    s += __shfl_xor(s,1);  s += __shfl_xor(s,2);
    ss += __shfl_xor(ss,1); ss += __shfl_xor(ss,2);
    float mu  = s*(1.f/256.f);
    float inv = 1.f/sqrtf(ss*(1.f/256.f) - mu*mu + 1e-5f);
    const float4* gv4 = (const float4*)(lng + part*64);
    const float4* bv4 = (const float4*)(lnb + part*64);
    ushort4* xhrow = (ushort4*)(xh + (size_t)(tb+t4)*256 + part*64);
    #pragma unroll 4
    for (int j=0;j<16;++j){
      float4 v = xrow[j];
      float4 gv = gv4[j], bv = bv4[j];
      float xn[4] = { (v.x-mu)*inv*gv.x+bv.x, (v.y-mu)*inv*gv.y+bv.y,
                      (v.z-mu)*inv*gv.z+bv.z, (v.w-mu)*inv*gv.w+bv.w };
      u16 h[4], l[4];
      #pragma unroll
      for (int q=0;q<4;++q){ h[q]=f2bf(xn[q]); l[q]=f2bf(xn[q]-bf2f(h[q])); }
      ushort4 hh = make_ushort4(h[0],h[1],h[2],h[3]);
      ushort4 ll = make_ushort4(l[0],l[1],l[2],l[3]);
      xhrow[j] = hh;
      *(ushort4*)&ash[t4*264 + part*64 + j*4] = hh;
      *(ushort4*)&asl[t4*264 + part*64 + j*4] = ll;
    }
  }
  __syncthreads();
  f32x4 acc[4][4];
  #pragma unroll
  for (int mf=0;mf<4;++mf)
    #pragma unroll
    for (int nf=0;nf<4;++nf) acc[mf][nf] = (f32x4){0.f,0.f,0.f,0.f};

  const u16* bhb = rwh + (size_t)wv*64*256;
  const u16* blb = rwl + (size_t)wv*64*256;
  #pragma unroll
  for (int kt=0;kt<8;++kt){
    bf16x8 ah[4], al[4], bh[4], bl[4];
    #pragma unroll
    for (int nf=0;nf<4;++nf){
      bh[nf] = *(const bf16x8*)(bhb + (size_t)(nf*16+lr)*256 + kt*32 + lg*8);
      bl[nf] = *(const bf16x8*)(blb + (size_t)(nf*16+lr)*256 + kt*32 + lg*8);
    }
    #pragma unroll
    for (int mf=0;mf<4;++mf){
      ah[mf] = *(const bf16x8*)(&ash[(mf*16+lr)*264 + kt*32 + lg*8]);
      al[mf] = *(const bf16x8*)(&asl[(mf*16+lr)*264 + kt*32 + lg*8]);
    }
    #pragma unroll
    for (int mf=0;mf<4;++mf)
      #pragma unroll
      for (int nf=0;nf<4;++nf){
        acc[mf][nf] = MFMA(ah[mf], bh[nf], acc[mf][nf]);
        acc[mf][nf] = MFMA(al[mf], bh[nf], acc[mf][nf]);
        acc[mf][nf] = MFMA(ah[mf], bl[nf], acc[mf][nf]);
      }
  }
  __syncthreads();   // all waves done reading ash/asl before fbuf overwrite
  int b = tb >> 12;
  #pragma unroll
  for (int mf=0;mf<4;++mf)
    #pragma unroll
    for (int nf=0;nf<4;++nf){
      int j = wv*64 + nf*16 + lr;
      float rbv = regb[b*256 + j];
      #pragma unroll
      for (int r=0;r<4;++r){
        int tl_ = mf*16 + lg*4 + r;
        float v = acc[mf][nf][r] + rbv;
        fbuf[tl_*257 + j] = v/(1.f+__expf(-v));
      }
    }
  __syncthreads();   // hid ready in LDS
  // ---- logits: 4 lanes per token ----
  int t4 = tid >> 2, part = tid & 3;
  float lacc[6] = {0.f,0.f,0.f,0.f,0.f,0.f};
  const float* hrow = fbuf + t4*257 + part*64;
  for (int jj=0;jj<64;++jj){
    float hv = hrow[jj];
    int j = part*64 + jj;
    #pragma unroll
    for (int e=0;e<6;++e) lacc[e] += hv*rw2[j*6+e];
  }
  #pragma unroll
  for (int m=1;m<4;m<<=1)
    #pragma unroll
    for (int e=0;e<6;++e) lacc[e] += __shfl_xor(lacc[e], m);
  int pid=0, q=0;
  float gmin=0.f, gmax=0.f;
  if (part == 0){
    float lgv[6];
    #pragma unroll
    for (int e=0;e<6;++e) lgv[e] = lacc[e] + rb2[e];
    int i0=0; float v0=lgv[0];
    #pragma unroll
    for (int e=1;e<6;++e) if (lgv[e] > v0){ v0=lgv[e]; i0=e; }
    int i1=-1; float v1=-1e30f;
    #pragma unroll
    for (int e=0;e<6;++e) if (e!=i0 && lgv[e] > v1){ v1=lgv[e]; i1=e; }
    float ex = expf(v1-v0);
    float w0 = 1.f/(1.f+ex), w1v = ex/(1.f+ex);
    int emin = min(i0,i1), emax = max(i0,i1);
    pid = emin*5 - ((emin*(emin-1))>>1) + (emax-emin-1);
    gmin = (i0<i1)? w0 : w1v;
    gmax = (i0<i1)? w1v : w0;
    q = atomicAdd(&lcnt[pid], 1);
    float ps=0.f, p[6];
    #pragma unroll
    for (int e=0;e<6;++e){ p[e]=expf(lgv[e]-v0); ps+=p[e]; }
    float rinv = 1.f/ps;
    #pragma unroll
    for (int e=0;e<6;++e) atomicAdd(&psum[e], p[e]*rinv);
    atomicAdd(&pcnt[i0], 1.f);
  }
  __syncthreads();
  if (tid < 15) lbase[tid] = atomicAdd(&cnt[tid], lcnt[tid]);
  __syncthreads();
  if (part == 0){
    int pos = pid*32768 + lbase[pid] + q;
    list[pos] = tb + t4;
    gl2[pos] = make_float2(gmin, gmax);
  }
  if (tid < 6){
    partials[blockIdx.x*12 + tid] = psum[tid];
    partials[blockIdx.x*12 + 6 + tid] = pcnt[tid];
  }
}

// ---------- pair-sparse expert MLP: block = (pair, 64-token chunk); writes out directly ----------
// LDS 64KB -> 2 blocks/CU. xs [s<32][tok<64] at 0; hs at +16384 (r11-verified layout).
// Last block (bid == gridDim-1) computes the aux loss.
__global__ __launch_bounds__(512,2) void k_experts(const u16* __restrict__ xh,
        const u16* __restrict__ w1t2, const u16* __restrict__ w2t2,
        const float* __restrict__ b1g, const float* __restrict__ b2g,
        const int* __restrict__ list, const float2* __restrict__ gl2,
        const int* __restrict__ cnt, const float* __restrict__ xg,
        float* __restrict__ outp, const float* __restrict__ partials){
  int tid = threadIdx.x;
  int bid = blockIdx.x;
  if (bid == gridDim.x - 1){
    // ---- aux loss ----
    __shared__ float a[12];
    if (tid < 12) a[tid] = 0.f;
    __syncthreads();
    int col = tid & 15, seg = tid >> 4;   // 32 segments
    if (col < 12){
      float s = 0.f;
      for (int i=seg; i<512; i+=32) s += partials[i*12+col];
      atomicAdd(&a[col], s);
    }
    __syncthreads();
    if (tid==0){
      float aux=0.f;
      #pragma unroll
      for (int e=0;e<6;++e) aux += a[e]*a[6+e];
      aux *= 0.01f*6.f/(32768.f*32768.f);
      outp[8388608] = aux;
    }
    return;
  }
  // ---- map bid -> (pair, chunk) via prefix walk ----
  int pid = -1, chunk = 0, acc = 0;
  #pragma unroll
  for (int p=0;p<15;++p){
    int c = (cnt[p] + 63) >> 6;
    if (pid < 0){
      if (bid < acc + c){ pid = p; chunk = bid - acc; }
      acc += c;
    }
  }
  if (pid < 0) return;
  const int pe0[15] = {0,0,0,0,0,1,1,1,1,2,2,2,3,3,4};
  const int pe1[15] = {1,2,3,4,5,2,3,4,5,3,4,5,4,5,5};
  int e0 = pe0[pid], e1 = pe1[pid];
  int cnte = cnt[pid];
  int gbase = chunk << 6;

  __shared__ u16 lds[32768];     // xs 32KB | hs 32KB
  __shared__ int tkid[64];
  __shared__ float tg[2][64];
  int lane = tid & 63, wv = tid >> 6;
  int l31 = lane & 31, l5 = lane >> 5;

  if (tid < 64){
    int p = gbase + tid;
    int cl = (p < cnte) ? p : (cnte - 1);
    tkid[tid] = list[pid*32768 + cl];
    float2 g = (p < cnte) ? gl2[pid*32768 + p] : make_float2(0.f, 0.f);
    tg[0][tid] = g.x; tg[1][tid] = g.y;
  }
  __syncthreads();
  // gather xs: linear LDS dest (slot-major), per-lane global source rows
  #pragma unroll
  for (int it=0; it<4; ++it){
    int gcell = it*512 + tid;
    int s = gcell >> 6, tok = gcell & 63;
    gll16(xh + (size_t)tkid[tok]*256 + s*8, lds + gcell*8);
  }
  __syncthreads();

  f32x16 a2t0 = (f32x16)(0.f), a2t1 = (f32x16)(0.f);

  #pragma unroll
  for (int ei=0; ei<2; ++ei){
    int e = ei ? e1 : e0;
    #pragma unroll
    for (int hh=0;hh<2;++hh){
      // ---- GEMM1: wave owns 32 h-rows (hh*256 + wv*32), K=256, depth-4 prefetch ----
      f32x16 a1t0 = (f32x16)(0.f), a1t1 = (f32x16)(0.f);
      const u16* w1b = w1t2 + (size_t)e*131072 + (size_t)(hh*256 + wv*32 + l31)*16 + l5*8;
      {
        bf16x8 p0 = *(const bf16x8*)(w1b);
        bf16x8 p1 = *(const bf16x8*)(w1b + 8192);
        bf16x8 p2 = *(const bf16x8*)(w1b + 16384);
        bf16x8 p3 = *(const bf16x8*)(w1b + 24576);
        #pragma unroll
        for (int ks=0; ks<16; ++ks){
          bf16x8 cur = p0; p0 = p1; p1 = p2; p2 = p3;
          if (ks+4 < 16) p3 = *(const bf16x8*)(w1b + (ks+4)*8192);
          bf16x8 bx0 = *(const bf16x8*)&lds[(ks*2+l5)*512 + l31*8];
          bf16x8 bx1 = *(const bf16x8*)&lds[(ks*2+l5)*512 + (l31+32)*8];
          a1t0 = MFMA32(cur, bx0, a1t0);
          a1t1 = MFMA32(cur, bx1, a1t1);
        }
      }
      __syncthreads();   // previous hs readers done
      // ---- epilogue: bias + silu, scaled by gate -> hs (cvt_pk pack) ----
      {
        float g0 = tg[ei][l31];
        float g1 = tg[ei][32+l31];
        #pragma unroll
        for (int rq=0;rq<4;++rq){
          float4 b4 = *(const float4*)(b1g + (size_t)e*512 + hh*256 + wv*32 + rq*8 + l5*4);
          float bb[4] = {b4.x,b4.y,b4.z,b4.w};
          float sv0[4], sv1[4];
          #pragma unroll
          for (int qq=0;qq<4;++qq){
            float v0 = a1t0[rq*4+qq] + bb[qq];
            float v1 = a1t1[rq*4+qq] + bb[qq];
            sv0[qq] = g0 * (v0/(1.f+__expf(-v0)));
            sv1[qq] = g1 * (v1/(1.f+__expf(-v1)));
          }
          unsigned pA, pB, pC, pD;
          asm("v_cvt_pk_bf16_f32 %0, %1, %2" : "=v"(pA) : "v"(sv0[0]), "v"(sv0[1]));
          asm("v_cvt_pk_bf16_f32 %0, %1, %2" : "=v"(pB) : "v"(sv0[2]), "v"(sv0[3]));
          asm("v_cvt_pk_bf16_f32 %0, %1, %2" : "=v"(pC) : "v"(sv1[0]), "v"(sv1[1]));
          asm("v_cvt_pk_bf16_f32 %0, %1, %2" : "=v"(pD) : "v"(sv1[2]), "v"(sv1[3]));
          int sbase = 16384 + (wv*4+rq)*512 + l5*4;
          *(uint2*)&lds[sbase + l31*8]      = make_uint2(pA,pB);
          *(uint2*)&lds[sbase + (l31+32)*8] = make_uint2(pC,pD);
        }
      }
      __syncthreads();   // hs ready
      // ---- GEMM2: wave owns 32 d-rows, K = this h-half (256), accumulate ----
      const u16* w2b = w2t2 + (size_t)e*131072 + (size_t)(hh*16)*4096 + (size_t)(wv*32 + l31)*16 + l5*8;
      {
        bf16x8 p0 = *(const bf16x8*)(w2b);
        bf16x8 p1 = *(const bf16x8*)(w2b + 4096);
        bf16x8 p2 = *(const bf16x8*)(w2b + 8192);
        bf16x8 p3 = *(const bf16x8*)(w2b + 12288);
        #pragma unroll
        for (int ks=0; ks<16; ++ks){
          bf16x8 cur = p0; p0 = p1; p1 = p2; p2 = p3;
          if (ks+4 < 16) p3 = *(const bf16x8*)(w2b + (ks+4)*4096);
          bf16x8 h0 = *(const bf16x8*)&lds[16384 + (ks*2+l5)*512 + l31*8];
          bf16x8 h1 = *(const bf16x8*)&lds[16384 + (ks*2+l5)*512 + (l31+32)*8];
          a2t0 = MFMA32(cur, h0, a2t0);
          a2t1 = MFMA32(cur, h1, a2t1);
        }
      }
    }
  }
  // ---- g*b2 fold for both experts ----
  {
    float g00 = tg[0][l31],    g10 = tg[1][l31];
    float g01 = tg[0][32+l31], g11 = tg[1][32+l31];
    #pragma unroll
    for (int rq=0;rq<4;++rq){
      float4 ba = *(const float4*)(b2g + (size_t)e0*256 + wv*32 + rq*8 + l5*4);
      float4 bbv = *(const float4*)(b2g + (size_t)e1*256 + wv*32 + rq*8 + l5*4);
      a2t0[rq*4+0] += g00*ba.x + g10*bbv.x; a2t0[rq*4+1] += g00*ba.y + g10*bbv.y;
      a2t0[rq*4+2] += g00*ba.z + g10*bbv.z; a2t0[rq*4+3] += g00*ba.w + g10*bbv.w;
      a2t1[rq*4+0] += g01*ba.x + g11*bbv.x; a2t1[rq*4+1] += g01*ba.y + g11*bbv.y;
      a2t1[rq*4+2] += g01*ba.z + g11*bbv.z; a2t1[rq*4+3] += g01*ba.w + g11*bbv.w;
    }
  }
  // ---- residual + direct scattered store (each token written by exactly one block) ----
  {
    int t0 = tkid[l31], t1 = tkid[32+l31];
    bool v0 = (gbase + l31) < cnte;
    bool v1 = (gbase + 32 + l31) < cnte;
    #pragma unroll
    for (int rq=0;rq<4;++rq){
      int d = wv*32 + rq*8 + l5*4;
      if (v0){
        float4 xv = *(const float4*)(xg + (size_t)t0*256 + d);
        float4 o;
        o.x = xv.x + a2t0[rq*4+0]; o.y = xv.y + a2t0[rq*4+1];
        o.z = xv.z + a2t0[rq*4+2]; o.w = xv.w + a2t0[rq*4+3];
        *(float4*)(outp + (size_t)t0*256 + d) = o;
      }
      if (v1){
        float4 xv = *(const float4*)(xg + (size_t)t1*256 + d);
        float4 o;
        o.x = xv.x + a2t1[rq*4+0]; o.y = xv.y + a2t1[rq*4+1];
        o.z = xv.z + a2t1[rq*4+2]; o.w = xv.w + a2t1[rq*4+3];
        *(float4*)(outp + (size_t)t1*256 + d) = o;
      }
    }
  }
}

extern "C" void kernel_launch(void* const* d_in, const int* in_sizes, int n_in,
                              void* d_out, int out_size, void* d_ws, size_t ws_size,
                              hipStream_t stream){
  const float* x      = (const float*)d_in[0];
  const float* regime = (const float*)d_in[1];
  const float* ln_g   = (const float*)d_in[2];
  const float* ln_b   = (const float*)d_in[3];
  const float* w1     = (const float*)d_in[4];
  const float* b1     = (const float*)d_in[5];
  const float* w2     = (const float*)d_in[6];
  const float* b2     = (const float*)d_in[7];
  const float* rw1    = (const float*)d_in[8];
  const float* rb1    = (const float*)d_in[9];
  const float* rw2    = (const float*)d_in[10];
  const float* rb2    = (const float*)d_in[11];
  float* outp = (float*)d_out;
  char* ws = (char*)d_ws;

  u16*    w1t2 = (u16*)(ws + 0);          // 1,572,864
  u16*    w2t2 = (u16*)(ws + 1572864);    // 1,572,864
  u16*    rwh  = (u16*)(ws + 3145728);    // 131,072
  u16*    rwl  = (u16*)(ws + 3276800);    // 131,072
  float*  regb = (float*)(ws + 3407872);  // 8,192
  u16*    xh   = (u16*)(ws + 3416064);    // 16,777,216 -> 20,193,280
  int*    cnt  = (int*)(ws + 20193280);   // 60 (pad 256)
  int*    list = (int*)(ws + 20193536);   // 15*32768*4 = 1,966,080
  float2* gl2  = (float2*)(ws + 22159616);// 15*32768*8 = 3,932,160
  float*  part = (float*)(ws + 26091776); // 24,576

  hipMemsetAsync(cnt, 0, 64, stream);
  k_prep_rw1<<<264,256,0,stream>>>(rw1, rb1, regime, rwh, rwl, regb);
  k_router<<<896,256,0,stream>>>(x, ln_g, ln_b, rwh, rwl, regb, rw2, rb2,
                                 xh, list, gl2, cnt, part, w1, w2, w1t2, w2t2);
  k_experts<<<545,512,0,stream>>>(xh, w1t2, w2t2, b1, b2, list, gl2, cnt, x, outp, part);
}

// Round 19
// 155.973 us; speedup vs baseline: 1.4359x; 1.0846x over previous
//
#include <hip/hip_runtime.h>
#include <cmath>

typedef unsigned short u16;
typedef __attribute__((ext_vector_type(8))) short bf16x8;
typedef __attribute__((ext_vector_type(4))) float f32x4;
typedef __attribute__((ext_vector_type(16))) float f32x16;

#define MFMA(a,b,c)   __builtin_amdgcn_mfma_f32_16x16x32_bf16((a),(b),(c),0,0,0)
#define MFMA32(a,b,c) __builtin_amdgcn_mfma_f32_32x32x16_bf16((a),(b),(c),0,0,0)

__device__ __forceinline__ float bf2f(u16 u){ return __uint_as_float(((unsigned)u)<<16); }
__device__ __forceinline__ u16 f2bf(float f){
  unsigned x = __float_as_uint(f);
  return (u16)((x + 0x7FFFu + ((x>>16)&1u)) >> 16);
}

__device__ __forceinline__ void gll16(const u16* g, u16* l){
  __builtin_amdgcn_global_load_lds((const __attribute__((address_space(1))) unsigned*)g,
                                   (__attribute__((address_space(3))) unsigned*)l, 16, 0, 0);
}

// ---------- small prep: rw1 hi/lo split (SLAB layout [kt][j][32]) + regime bias fold ----------
__global__ void k_prep_rw1(const float* __restrict__ rw1, const float* __restrict__ rb1,
                           const float* __restrict__ regime,
                           u16* __restrict__ rwh, u16* __restrict__ rwl,
                           float* __restrict__ regb){
  int idx = blockIdx.x*256 + threadIdx.x;
  if (idx < 65536){
    int dd = idx & 255, j = idx >> 8;
    float w = rw1[dd*256 + j];
    u16 hi = f2bf(w);
    int pos = (dd>>5)*8192 + j*32 + (dd&31);   // slab: fragment load = 1KB contiguous
    rwh[pos] = hi;
    rwl[pos] = f2bf(w - bf2f(hi));
  } else {
    int i = idx - 65536; int j = i & 255, bb = i >> 8;
    float v = rb1[j];
    #pragma unroll
    for (int r=0;r<5;++r) v += regime[bb*5+r]*rw1[(256+r)*256 + j];
    regb[bb*256 + j] = v;
  }
}

// ---------- fused LN + router GEMM + logits + top2 + PAIR-list build + aux partials
// ---------- blocks >= 512: w1/w2 transpose/re-layout (independent; needed only by experts)
__global__ __launch_bounds__(256,2) void k_router(const float* __restrict__ x,
        const float* __restrict__ lng, const float* __restrict__ lnb,
        const u16* __restrict__ rwh, const u16* __restrict__ rwl,
        const float* __restrict__ regb,
        const float* __restrict__ rw2, const float* __restrict__ rb2,
        u16* __restrict__ xh, int* __restrict__ list, float2* __restrict__ gl2,
        int* __restrict__ cnt, float* __restrict__ partials,
        const float* __restrict__ w1, const float* __restrict__ w2,
        u16* __restrict__ w1t2, u16* __restrict__ w2t2){
  __shared__ __align__(16) u16 buf[33792];   // ash | asl, reused as fbuf / transpose tile
  __shared__ float psum[6], pcnt[6];
  __shared__ int lcnt[15], lbase[15];
  int tid = threadIdx.x;
  if (blockIdx.x >= 512){
    int b = blockIdx.x - 512;
    u16 (*t)[66] = (u16(*)[66])buf;
    int c0 = tid & 63, r0 = tid >> 6;
    if (b < 192){          // w1 (E,D,H) -> w1t2[e][kd][h][d&15]
      int e = b >> 5, tl = b & 31;
      int tr = (tl >> 3) << 6, tc = (tl & 7) << 6;
      const float* src = w1 + (size_t)e*131072;
      u16* dst = w1t2 + (size_t)e*131072;
      #pragma unroll
      for (int i=0;i<16;++i){
        int r = r0 + i*4;
        t[c0][r] = f2bf(src[(size_t)(tr+r)*512 + tc + c0]);
      }
      __syncthreads();
      #pragma unroll
      for (int i=0;i<16;++i){
        int cc = r0 + i*4;
        int h = tc + cc, d = tr + c0;
        dst[(size_t)((d>>4)*512 + h)*16 + (d&15)] = t[cc][c0];
      }
    } else {               // w2 (E,H,D) -> w2t2[e][kh][d][h&15]
      int bb = b - 192;
      int e = bb >> 5, tl = bb & 31;
      int tr = (tl >> 2) << 6, tc = (tl & 3) << 6;
      const float* src = w2 + (size_t)e*131072;
      u16* dst = w2t2 + (size_t)e*131072;
      #pragma unroll
      for (int i=0;i<16;++i){
        int r = r0 + i*4;
        t[c0][r] = f2bf(src[(size_t)(tr+r)*256 + tc + c0]);
      }
      __syncthreads();
      #pragma unroll
      for (int i=0;i<16;++i){
        int cc = r0 + i*4;
        int d = tc + cc, h = tr + c0;
        dst[(size_t)((h>>4)*256 + d)*16 + (h&15)] = t[cc][c0];
      }
    }
    return;
  }
  u16* ash = buf;
  u16* asl = buf + 16896;
  float* fbuf = (float*)buf;                  // [t][j], row stride 257 f32
  if (tid < 6){ psum[tid]=0.f; pcnt[tid]=0.f; }
  if (tid < 15) lcnt[tid]=0;
  int lane = tid & 63, wv = tid >> 6;
  int lr = lane & 15, lg = lane >> 4;
  int tb = blockIdx.x * 64;
  // ---- LayerNorm (4 threads per token), write hi/lo to LDS + xh to global ----
  {
    int t4 = tid >> 2, part = tid & 3;
    const float4* xrow = (const float4*)(x + (size_t)(tb+t4)*256 + part*64);
    float s=0.f, ss=0.f;
    #pragma unroll 4
    for (int j=0;j<16;++j){
      float4 v = xrow[j];
      s  += v.x+v.y+v.z+v.w;
      ss += v.x*v.x+v.y*v.y+v.z*v.z+v.w*v.w;
    }
    s += __shfl_xor(s,1);  s += __shfl_xor(s,2);
    ss += __shfl_xor(ss,1); ss += __shfl_xor(ss,2);
    float mu  = s*(1.f/256.f);
    float inv = 1.f/sqrtf(ss*(1.f/256.f) - mu*mu + 1e-5f);
    const float4* gv4 = (const float4*)(lng + part*64);
    const float4* bv4 = (const float4*)(lnb + part*64);
    ushort4* xhrow = (ushort4*)(xh + (size_t)(tb+t4)*256 + part*64);
    #pragma unroll 4
    for (int j=0;j<16;++j){
      float4 v = xrow[j];
      float4 gv = gv4[j], bv = bv4[j];
      float xn[4] = { (v.x-mu)*inv*gv.x+bv.x, (v.y-mu)*inv*gv.y+bv.y,
                      (v.z-mu)*inv*gv.z+bv.z, (v.w-mu)*inv*gv.w+bv.w };
      u16 h[4], l[4];
      #pragma unroll
      for (int q=0;q<4;++q){ h[q]=f2bf(xn[q]); l[q]=f2bf(xn[q]-bf2f(h[q])); }
      ushort4 hh = make_ushort4(h[0],h[1],h[2],h[3]);
      ushort4 ll = make_ushort4(l[0],l[1],l[2],l[3]);
      xhrow[j] = hh;
      *(ushort4*)&ash[t4*264 + part*64 + j*4] = hh;
      *(ushort4*)&asl[t4*264 + part*64 + j*4] = ll;
    }
  }
  __syncthreads();
  f32x4 acc[4][4];
  #pragma unroll
  for (int mf=0;mf<4;++mf)
    #pragma unroll
    for (int nf=0;nf<4;++nf) acc[mf][nf] = (f32x4){0.f,0.f,0.f,0.f};

  #pragma unroll
  for (int kt=0;kt<8;++kt){
    bf16x8 ah[4], al[4], bh[4], bl[4];
    #pragma unroll
    for (int nf=0;nf<4;++nf){
      int jaddr = kt*8192 + (wv*64 + nf*16 + lr)*32 + lg*8;   // slab: coalesced 1KB frags
      bh[nf] = *(const bf16x8*)(rwh + jaddr);
      bl[nf] = *(const bf16x8*)(rwl + jaddr);
    }
    #pragma unroll
    for (int mf=0;mf<4;++mf){
      ah[mf] = *(const bf16x8*)(&ash[(mf*16+lr)*264 + kt*32 + lg*8]);
      al[mf] = *(const bf16x8*)(&asl[(mf*16+lr)*264 + kt*32 + lg*8]);
    }
    #pragma unroll
    for (int mf=0;mf<4;++mf)
      #pragma unroll
      for (int nf=0;nf<4;++nf){
        acc[mf][nf] = MFMA(ah[mf], bh[nf], acc[mf][nf]);
        acc[mf][nf] = MFMA(al[mf], bh[nf], acc[mf][nf]);
        acc[mf][nf] = MFMA(ah[mf], bl[nf], acc[mf][nf]);
      }
  }
  __syncthreads();   // all waves done reading ash/asl before fbuf overwrite
  int b = tb >> 12;
  #pragma unroll
  for (int mf=0;mf<4;++mf)
    #pragma unroll
    for (int nf=0;nf<4;++nf){
      int j = wv*64 + nf*16 + lr;
      float rbv = regb[b*256 + j];
      #pragma unroll
      for (int r=0;r<4;++r){
        int tl_ = mf*16 + lg*4 + r;
        float v = acc[mf][nf][r] + rbv;
        fbuf[tl_*257 + j] = v/(1.f+__expf(-v));
      }
    }
  __syncthreads();   // hid ready in LDS
  // ---- logits: 4 lanes per token ----
  int t4 = tid >> 2, part = tid & 3;
  float lacc[6] = {0.f,0.f,0.f,0.f,0.f,0.f};
  const float* hrow = fbuf + t4*257 + part*64;
  for (int jj=0;jj<64;++jj){
    float hv = hrow[jj];
    int j = part*64 + jj;
    #pragma unroll
    for (int e=0;e<6;++e) lacc[e] += hv*rw2[j*6+e];
  }
  #pragma unroll
  for (int m=1;m<4;m<<=1)
    #pragma unroll
    for (int e=0;e<6;++e) lacc[e] += __shfl_xor(lacc[e], m);
  int pid=0, q=0;
  float gmin=0.f, gmax=0.f;
  if (part == 0){
    float lgv[6];
    #pragma unroll
    for (int e=0;e<6;++e) lgv[e] = lacc[e] + rb2[e];
    int i0=0; float v0=lgv[0];
    #pragma unroll
    for (int e=1;e<6;++e) if (lgv[e] > v0){ v0=lgv[e]; i0=e; }
    int i1=-1; float v1=-1e30f;
    #pragma unroll
    for (int e=0;e<6;++e) if (e!=i0 && lgv[e] > v1){ v1=lgv[e]; i1=e; }
    float ex = expf(v1-v0);
    float w0 = 1.f/(1.f+ex), w1v = ex/(1.f+ex);
    int emin = min(i0,i1), emax = max(i0,i1);
    pid = emin*5 - ((emin*(emin-1))>>1) + (emax-emin-1);
    gmin = (i0<i1)? w0 : w1v;
    gmax = (i0<i1)? w1v : w0;
    q = atomicAdd(&lcnt[pid], 1);
    float ps=0.f, p[6];
    #pragma unroll
    for (int e=0;e<6;++e){ p[e]=expf(lgv[e]-v0); ps+=p[e]; }
    float rinv = 1.f/ps;
    #pragma unroll
    for (int e=0;e<6;++e) atomicAdd(&psum[e], p[e]*rinv);
    atomicAdd(&pcnt[i0], 1.f);
  }
  __syncthreads();
  if (tid < 15) lbase[tid] = atomicAdd(&cnt[tid], lcnt[tid]);
  __syncthreads();
  if (part == 0){
    int pos = pid*32768 + lbase[pid] + q;
    list[pos] = tb + t4;
    gl2[pos] = make_float2(gmin, gmax);
  }
  if (tid < 6){
    partials[blockIdx.x*12 + tid] = psum[tid];
    partials[blockIdx.x*12 + 6 + tid] = pcnt[tid];
  }
}

// ---------- pair-sparse expert MLP: block = (pair, 64-token chunk); direct out writes ----------
// LDS ~67.5KB -> 2 blocks/CU. xs [s<32][tok<64] at 0; hs at +16384 (r11-verified layout).
// Final store bounces a2 through LDS fb[tok][260] f32 (stride 260 >= D=256, 4-pad),
// then row-contiguous out = x + fb. Last block computes the aux loss.
__global__ __launch_bounds__(512,2) void k_experts(const u16* __restrict__ xh,
        const u16* __restrict__ w1t2, const u16* __restrict__ w2t2,
        const float* __restrict__ b1g, const float* __restrict__ b2g,
        const int* __restrict__ list, const float2* __restrict__ gl2,
        const int* __restrict__ cnt, const float* __restrict__ xg,
        float* __restrict__ outp, const float* __restrict__ partials){
  int tid = threadIdx.x;
  int bid = blockIdx.x;
  if (bid == gridDim.x - 1){
    __shared__ float a[12];
    if (tid < 12) a[tid] = 0.f;
    __syncthreads();
    int col = tid & 15, seg = tid >> 4;
    if (col < 12){
      float s = 0.f;
      for (int i=seg; i<512; i+=32) s += partials[i*12+col];
      atomicAdd(&a[col], s);
    }
    __syncthreads();
    if (tid==0){
      float aux=0.f;
      #pragma unroll
      for (int e=0;e<6;++e) aux += a[e]*a[6+e];
      aux *= 0.01f*6.f/(32768.f*32768.f);
      outp[8388608] = aux;
    }
    return;
  }
  int pid = -1, chunk = 0, acc = 0;
  #pragma unroll
  for (int p=0;p<15;++p){
    int c = (cnt[p] + 63) >> 6;
    if (pid < 0){
      if (bid < acc + c){ pid = p; chunk = bid - acc; }
      acc += c;
    }
  }
  if (pid < 0) return;
  const int pe0[15] = {0,0,0,0,0,1,1,1,1,2,2,2,3,3,4};
  const int pe1[15] = {1,2,3,4,5,2,3,4,5,3,4,5,4,5,5};
  int e0 = pe0[pid], e1 = pe1[pid];
  int cnte = cnt[pid];
  int gbase = chunk << 6;

  __shared__ u16 lds[33280];     // xs 32KB | hs 32KB; reused as fb[64][260] f32 (66,560B)
  __shared__ int tkid[64];
  __shared__ float tg[2][64];
  int lane = tid & 63, wv = tid >> 6;
  int l31 = lane & 31, l5 = lane >> 5;

  if (tid < 64){
    int p = gbase + tid;
    int cl = (p < cnte) ? p : (cnte - 1);
    tkid[tid] = list[pid*32768 + cl];
    float2 g = (p < cnte) ? gl2[pid*32768 + p] : make_float2(0.f, 0.f);
    tg[0][tid] = g.x; tg[1][tid] = g.y;
  }
  __syncthreads();
  #pragma unroll
  for (int it=0; it<4; ++it){
    int gcell = it*512 + tid;
    int s = gcell >> 6, tok = gcell & 63;
    gll16(xh + (size_t)tkid[tok]*256 + s*8, lds + gcell*8);
  }
  __syncthreads();

  f32x16 a2t0 = (f32x16)(0.f), a2t1 = (f32x16)(0.f);

  #pragma unroll
  for (int ei=0; ei<2; ++ei){
    int e = ei ? e1 : e0;
    #pragma unroll
    for (int hh=0;hh<2;++hh){
      // ---- GEMM1: wave owns 32 h-rows (hh*256 + wv*32), K=256, depth-4 prefetch ----
      f32x16 a1t0 = (f32x16)(0.f), a1t1 = (f32x16)(0.f);
      const u16* w1b = w1t2 + (size_t)e*131072 + (size_t)(hh*256 + wv*32 + l31)*16 + l5*8;
      {
        bf16x8 p0 = *(const bf16x8*)(w1b);
        bf16x8 p1 = *(const bf16x8*)(w1b + 8192);
        bf16x8 p2 = *(const bf16x8*)(w1b + 16384);
        bf16x8 p3 = *(const bf16x8*)(w1b + 24576);
        #pragma unroll
        for (int ks=0; ks<16; ++ks){
          bf16x8 cur = p0; p0 = p1; p1 = p2; p2 = p3;
          if (ks+4 < 16) p3 = *(const bf16x8*)(w1b + (ks+4)*8192);
          bf16x8 bx0 = *(const bf16x8*)&lds[(ks*2+l5)*512 + l31*8];
          bf16x8 bx1 = *(const bf16x8*)&lds[(ks*2+l5)*512 + (l31+32)*8];
          a1t0 = MFMA32(cur, bx0, a1t0);
          a1t1 = MFMA32(cur, bx1, a1t1);
        }
      }
      __syncthreads();   // previous hs readers done
      // ---- epilogue: bias + silu, scaled by gate -> hs (cvt_pk pack) ----
      {
        float g0 = tg[ei][l31];
        float g1 = tg[ei][32+l31];
        #pragma unroll
        for (int rq=0;rq<4;++rq){
          float4 b4 = *(const float4*)(b1g + (size_t)e*512 + hh*256 + wv*32 + rq*8 + l5*4);
          float bb[4] = {b4.x,b4.y,b4.z,b4.w};
          float sv0[4], sv1[4];
          #pragma unroll
          for (int qq=0;qq<4;++qq){
            float v0 = a1t0[rq*4+qq] + bb[qq];
            float v1 = a1t1[rq*4+qq] + bb[qq];
            sv0[qq] = g0 * (v0/(1.f+__expf(-v0)));
            sv1[qq] = g1 * (v1/(1.f+__expf(-v1)));
          }
          unsigned pA, pB, pC, pD;
          asm("v_cvt_pk_bf16_f32 %0, %1, %2" : "=v"(pA) : "v"(sv0[0]), "v"(sv0[1]));
          asm("v_cvt_pk_bf16_f32 %0, %1, %2" : "=v"(pB) : "v"(sv0[2]), "v"(sv0[3]));
          asm("v_cvt_pk_bf16_f32 %0, %1, %2" : "=v"(pC) : "v"(sv1[0]), "v"(sv1[1]));
          asm("v_cvt_pk_bf16_f32 %0, %1, %2" : "=v"(pD) : "v"(sv1[2]), "v"(sv1[3]));
          int sbase = 16384 + (wv*4+rq)*512 + l5*4;
          *(uint2*)&lds[sbase + l31*8]      = make_uint2(pA,pB);
          *(uint2*)&lds[sbase + (l31+32)*8] = make_uint2(pC,pD);
        }
      }
      __syncthreads();   // hs ready
      // ---- GEMM2: wave owns 32 d-rows, K = this h-half (256), accumulate ----
      const u16* w2b = w2t2 + (size_t)e*131072 + (size_t)(hh*16)*4096 + (size_t)(wv*32 + l31)*16 + l5*8;
      {
        bf16x8 p0 = *(const bf16x8*)(w2b);
        bf16x8 p1 = *(const bf16x8*)(w2b + 4096);
        bf16x8 p2 = *(const bf16x8*)(w2b + 8192);
        bf16x8 p3 = *(const bf16x8*)(w2b + 12288);
        #pragma unroll
        for (int ks=0; ks<16; ++ks){
          bf16x8 cur = p0; p0 = p1; p1 = p2; p2 = p3;
          if (ks+4 < 16) p3 = *(const bf16x8*)(w2b + (ks+4)*4096);
          bf16x8 h0 = *(const bf16x8*)&lds[16384 + (ks*2+l5)*512 + l31*8];
          bf16x8 h1 = *(const bf16x8*)&lds[16384 + (ks*2+l5)*512 + (l31+32)*8];
          a2t0 = MFMA32(cur, h0, a2t0);
          a2t1 = MFMA32(cur, h1, a2t1);
        }
      }
    }
  }
  // ---- g*b2 fold for both experts ----
  {
    float g00 = tg[0][l31],    g10 = tg[1][l31];
    float g01 = tg[0][32+l31], g11 = tg[1][32+l31];
    #pragma unroll
    for (int rq=0;rq<4;++rq){
      float4 ba = *(const float4*)(b2g + (size_t)e0*256 + wv*32 + rq*8 + l5*4);
      float4 bbv = *(const float4*)(b2g + (size_t)e1*256 + wv*32 + rq*8 + l5*4);
      a2t0[rq*4+0] += g00*ba.x + g10*bbv.x; a2t0[rq*4+1] += g00*ba.y + g10*bbv.y;
      a2t0[rq*4+2] += g00*ba.z + g10*bbv.z; a2t0[rq*4+3] += g00*ba.w + g10*bbv.w;
      a2t1[rq*4+0] += g01*ba.x + g11*bbv.x; a2t1[rq*4+1] += g01*ba.y + g11*bbv.y;
      a2t1[rq*4+2] += g01*ba.z + g11*bbv.z; a2t1[rq*4+3] += g01*ba.w + g11*bbv.w;
    }
  }
  // ---- bounce a2 -> LDS fb[tok][260] f32, then row-contiguous residual+store ----
  __syncthreads();                 // all GEMM2 LDS reads done; fb overwrites xs/hs
  float* fb = (float*)lds;         // 64 x 260 f32 = 66,560 B
  #pragma unroll
  for (int rq=0;rq<4;++rq){
    int d = wv*32 + rq*8 + l5*4;
    *(float4*)&fb[l31*260 + d]      = make_float4(a2t0[rq*4+0],a2t0[rq*4+1],a2t0[rq*4+2],a2t0[rq*4+3]);
    *(float4*)&fb[(32+l31)*260 + d] = make_float4(a2t1[rq*4+0],a2t1[rq*4+1],a2t1[rq*4+2],a2t1[rq*4+3]);
  }
  __syncthreads();
  for (int i = tid; i < 4096; i += 512){
    int row = i >> 6, seg = i & 63;
    if (gbase + row < cnte){
      int t = tkid[row];
      float4 fv = *(float4*)&fb[row*260 + seg*4];
      float4 xv = *(const float4*)(xg + (size_t)t*256 + seg*4);
      float4 o;
      o.x = xv.x + fv.x; o.y = xv.y + fv.y; o.z = xv.z + fv.z; o.w = xv.w + fv.w;
      *(float4*)(outp + (size_t)t*256 + seg*4) = o;
    }
  }
}

extern "C" void kernel_launch(void* const* d_in, const int* in_sizes, int n_in,
                              void* d_out, int out_size, void* d_ws, size_t ws_size,
                              hipStream_t stream){
  const float* x      = (const float*)d_in[0];
  const float* regime = (const float*)d_in[1];
  const float* ln_g   = (const float*)d_in[2];
  const float* ln_b   = (const float*)d_in[3];
  const float* w1     = (const float*)d_in[4];
  const float* b1     = (const float*)d_in[5];
  const float* w2     = (const float*)d_in[6];
  const float* b2     = (const float*)d_in[7];
  const float* rw1    = (const float*)d_in[8];
  const float* rb1    = (const float*)d_in[9];
  const float* rw2    = (const float*)d_in[10];
  const float* rb2    = (const float*)d_in[11];
  float* outp = (float*)d_out;
  char* ws = (char*)d_ws;

  u16*    w1t2 = (u16*)(ws + 0);          // 1,572,864
  u16*    w2t2 = (u16*)(ws + 1572864);    // 1,572,864
  u16*    rwh  = (u16*)(ws + 3145728);    // 131,072
  u16*    rwl  = (u16*)(ws + 3276800);    // 131,072
  float*  regb = (float*)(ws + 3407872);  // 8,192
  u16*    xh   = (u16*)(ws + 3416064);    // 16,777,216 -> 20,193,280
  int*    cnt  = (int*)(ws + 20193280);   // 60 (pad 256)
  int*    list = (int*)(ws + 20193536);   // 1,966,080
  float2* gl2  = (float2*)(ws + 22159616);// 3,932,160
  float*  part = (float*)(ws + 26091776); // 24,576

  hipMemsetAsync(cnt, 0, 64, stream);
  k_prep_rw1<<<264,256,0,stream>>>(rw1, rb1, regime, rwh, rwl, regb);
  k_router<<<896,256,0,stream>>>(x, ln_g, ln_b, rwh, rwl, regb, rw2, rb2,
                                 xh, list, gl2, cnt, part, w1, w2, w1t2, w2t2);
  k_experts<<<545,512,0,stream>>>(xh, w1t2, w2t2, b1, b2, list, gl2, cnt, x, outp, part);
}